// Round 1
// baseline (357.948 us; speedup 1.0000x reference)
//
#include <hip/hip_runtime.h>
#include <math.h>

#define BATCH 128
#define SEQ   2048
#define HID   1024
#define CDIM  256

// ---------------------------------------------------------------------------
// Kernel 1: partial masked sums over a chunk of the sequence.
// grid (BATCH, SPLIT), block 256. Thread t owns float4 at h = t*4 (256*4 = HID).
// ---------------------------------------------------------------------------
__global__ __launch_bounds__(256) void pool_partial_kernel(
    const float* __restrict__ feat, const int* __restrict__ mask,
    float* __restrict__ partial, int rows_per, int split)
{
    const int b     = blockIdx.x;
    const int chunk = blockIdx.y;
    const int t     = threadIdx.x;

    const float4* fp = reinterpret_cast<const float4*>(feat) +
                       ((size_t)b * SEQ + (size_t)chunk * rows_per) * (HID / 4);
    const int* mp = mask + (size_t)b * SEQ + (size_t)chunk * rows_per;

    float ax = 0.f, ay = 0.f, az = 0.f, aw = 0.f;
    #pragma unroll 4
    for (int s = 0; s < rows_per; ++s) {
        const float m = (float)mp[s];          // wave-uniform broadcast load
        const float4 v = fp[(size_t)s * (HID / 4) + t];
        ax = fmaf(v.x, m, ax);
        ay = fmaf(v.y, m, ay);
        az = fmaf(v.z, m, az);
        aw = fmaf(v.w, m, aw);
    }
    float4 o; o.x = ax; o.y = ay; o.z = az; o.w = aw;
    reinterpret_cast<float4*>(partial)[((size_t)b * split + chunk) * (HID / 4) + t] = o;
}

// ---------------------------------------------------------------------------
// Kernel 2: per-row mask counts (as float). grid BATCH, block 256.
// ---------------------------------------------------------------------------
__global__ __launch_bounds__(256) void mask_count_kernel(
    const int* __restrict__ mask, float* __restrict__ cnt)
{
    const int b = blockIdx.x;
    const int t = threadIdx.x;
    int local = 0;
    for (int s = t; s < SEQ; s += 256) local += mask[(size_t)b * SEQ + s];
    __shared__ int red[256];
    red[t] = local;
    __syncthreads();
    for (int off = 128; off > 0; off >>= 1) {
        if (t < off) red[t] += red[t + off];
        __syncthreads();
    }
    if (t == 0) cnt[b] = (float)red[0];
}

// ---------------------------------------------------------------------------
// Kernel 3: reduce partials, divide by count -> pooled [B,H].
// grid BATCH, block 256 (float4 per thread).
// ---------------------------------------------------------------------------
__global__ __launch_bounds__(256) void pool_final_kernel(
    const float* __restrict__ partial, const float* __restrict__ cnt,
    float* __restrict__ pooled, int split)
{
    const int b = blockIdx.x;
    const int t = threadIdx.x;
    float ax = 0.f, ay = 0.f, az = 0.f, aw = 0.f;
    for (int c = 0; c < split; ++c) {
        const float4 v = reinterpret_cast<const float4*>(partial)
                            [((size_t)b * split + c) * (HID / 4) + t];
        ax += v.x; ay += v.y; az += v.z; aw += v.w;
    }
    const float inv = 1.0f / cnt[b];
    float4 o; o.x = ax * inv; o.y = ay * inv; o.z = az * inv; o.w = aw * inv;
    reinterpret_cast<float4*>(pooled)[(size_t)b * (HID / 4) + t] = o;
}

// ---------------------------------------------------------------------------
// Kernel 4: h = relu(pooled @ W1 + b1).  W1 is [H,H] (in,out) row-major.
// grid (HID/256, BATCH/8), block 256. Each block: 8 batch rows x 256 cols.
// pooled rows staged in LDS (broadcast reads, conflict-free).
// ---------------------------------------------------------------------------
__global__ __launch_bounds__(256) void mlp1_kernel(
    const float* __restrict__ pooled, const float* __restrict__ W1,
    const float* __restrict__ b1, float* __restrict__ hout)
{
    __shared__ float ps[8 * HID];  // 32 KiB
    const int jc = blockIdx.x;
    const int b0 = blockIdx.y * 8;
    const int t  = threadIdx.x;

    const float4* src = reinterpret_cast<const float4*>(pooled + (size_t)b0 * HID);
    float4* dst = reinterpret_cast<float4*>(ps);
    for (int i = t; i < 8 * HID / 4; i += 256) dst[i] = src[i];
    __syncthreads();

    const int j = jc * 256 + t;
    float acc[8];
    #pragma unroll
    for (int r = 0; r < 8; ++r) acc[r] = 0.f;

    for (int k = 0; k < HID; k += 4) {
        float w0 = W1[(size_t)(k + 0) * HID + j];
        float w1 = W1[(size_t)(k + 1) * HID + j];
        float w2 = W1[(size_t)(k + 2) * HID + j];
        float w3 = W1[(size_t)(k + 3) * HID + j];
        #pragma unroll
        for (int r = 0; r < 8; ++r) {
            const float4 p = *reinterpret_cast<const float4*>(&ps[r * HID + k]);
            acc[r] = fmaf(p.x, w0, acc[r]);
            acc[r] = fmaf(p.y, w1, acc[r]);
            acc[r] = fmaf(p.z, w2, acc[r]);
            acc[r] = fmaf(p.w, w3, acc[r]);
        }
    }
    const float bias = b1[j];
    #pragma unroll
    for (int r = 0; r < 8; ++r)
        hout[(size_t)(b0 + r) * HID + j] = fmaxf(acc[r] + bias, 0.f);
}

// ---------------------------------------------------------------------------
// Kernel 5: proj = normalize(h @ W2 + b2). W2 is [H,C]. grid BATCH, block CDIM.
// Writes normalized proj directly into d_out.
// ---------------------------------------------------------------------------
__global__ __launch_bounds__(256) void mlp2_norm_kernel(
    const float* __restrict__ hin, const float* __restrict__ W2,
    const float* __restrict__ b2, float* __restrict__ proj)
{
    __shared__ float hs[HID];  // 4 KiB
    const int b = blockIdx.x;
    const int t = threadIdx.x;

    const float4* src = reinterpret_cast<const float4*>(hin + (size_t)b * HID);
    float4* dst = reinterpret_cast<float4*>(hs);
    for (int i = t; i < HID / 4; i += CDIM) dst[i] = src[i];
    __syncthreads();

    float acc = 0.f;
    for (int k = 0; k < HID; k += 4) {
        acc = fmaf(hs[k + 0], W2[(size_t)(k + 0) * CDIM + t], acc);
        acc = fmaf(hs[k + 1], W2[(size_t)(k + 1) * CDIM + t], acc);
        acc = fmaf(hs[k + 2], W2[(size_t)(k + 2) * CDIM + t], acc);
        acc = fmaf(hs[k + 3], W2[(size_t)(k + 3) * CDIM + t], acc);
    }
    acc += b2[t];

    __shared__ float red[CDIM];
    red[t] = acc * acc;
    __syncthreads();
    for (int off = CDIM / 2; off > 0; off >>= 1) {
        if (t < off) red[t] += red[t + off];
        __syncthreads();
    }
    const float norm = fmaxf(sqrtf(red[0]), 1e-12f);
    proj[(size_t)b * CDIM + t] = acc / norm;
}

// ---------------------------------------------------------------------------
// Kernel 6: sim[i,j] = dot(proj_i, proj_j) / T. grid BATCH, block BATCH.
// ---------------------------------------------------------------------------
__global__ __launch_bounds__(128) void sim_kernel(
    const float* __restrict__ proj, const float* __restrict__ temp,
    float* __restrict__ sim)
{
    __shared__ float pi[CDIM];
    const int i = blockIdx.x;
    const int j = threadIdx.x;
    for (int c = j; c < CDIM; c += BATCH) pi[c] = proj[(size_t)i * CDIM + c];
    __syncthreads();

    const float4* pj = reinterpret_cast<const float4*>(proj + (size_t)j * CDIM);
    float acc = 0.f;
    for (int c4 = 0; c4 < CDIM / 4; ++c4) {
        const float4 v = pj[c4];
        acc = fmaf(pi[c4 * 4 + 0], v.x, acc);
        acc = fmaf(pi[c4 * 4 + 1], v.y, acc);
        acc = fmaf(pi[c4 * 4 + 2], v.z, acc);
        acc = fmaf(pi[c4 * 4 + 3], v.w, acc);
    }
    sim[(size_t)i * BATCH + j] = acc / temp[0];
}

// ---------------------------------------------------------------------------
// Kernel 7: loss = mean_i [ cnt_i * lse_i - sum_j labels_ij * sim_ij ].
// Single block, 128 threads (thread i owns row i). Deterministic reduce.
// ---------------------------------------------------------------------------
__global__ __launch_bounds__(128) void loss_kernel(
    const float* __restrict__ sim, const int* __restrict__ lang,
    float* __restrict__ out)
{
    const int i = threadIdx.x;
    const float* row = sim + (size_t)i * BATCH;
    const int li = lang[i];

    float m = -INFINITY;
    for (int j = 0; j < BATCH; ++j) m = fmaxf(m, row[j]);
    float sum = 0.f;
    for (int j = 0; j < BATCH; ++j) sum += expf(row[j] - m);
    const float lse = m + logf(sum);

    float wsum = 0.f;
    int cntl = 0;
    for (int j = 0; j < BATCH; ++j) {
        if (lang[j] != li && j != i) { wsum += row[j]; cntl++; }
    }
    float loss_i = (float)cntl * lse - wsum;

    __shared__ float red[BATCH];
    red[i] = loss_i;
    __syncthreads();
    for (int off = BATCH / 2; off > 0; off >>= 1) {
        if (i < off) red[i] += red[i + off];
        __syncthreads();
    }
    if (i == 0) out[0] = red[0] / (float)BATCH;
}

// ---------------------------------------------------------------------------
extern "C" void kernel_launch(void* const* d_in, const int* in_sizes, int n_in,
                              void* d_out, int out_size, void* d_ws, size_t ws_size,
                              hipStream_t stream)
{
    const float* feat = (const float*)d_in[0];
    const float* W1   = (const float*)d_in[1];
    const float* b1   = (const float*)d_in[2];
    const float* W2   = (const float*)d_in[3];
    const float* b2   = (const float*)d_in[4];
    const float* temp = (const float*)d_in[5];
    const int*   lang = (const int*)d_in[6];
    const int*   amask= (const int*)d_in[7];
    float* out = (float*)d_out;
    float* ws  = (float*)d_ws;

    // pick largest split-K for pooling that fits the workspace
    int split = 16;
    while (split > 1) {
        size_t need = sizeof(float) * ((size_t)BATCH * split * HID + BATCH +
                                       2 * (size_t)BATCH * HID + (size_t)BATCH * BATCH);
        if (need <= ws_size) break;
        split >>= 1;
    }
    const int rows_per = SEQ / split;

    float* partial = ws;
    float* cnt     = partial + (size_t)BATCH * split * HID;
    float* pooled  = cnt + BATCH;
    float* hbuf    = pooled + (size_t)BATCH * HID;
    float* simbuf  = hbuf + (size_t)BATCH * HID;

    pool_partial_kernel<<<dim3(BATCH, split), 256, 0, stream>>>(feat, amask, partial, rows_per, split);
    mask_count_kernel<<<BATCH, 256, 0, stream>>>(amask, cnt);
    pool_final_kernel<<<BATCH, 256, 0, stream>>>(partial, cnt, pooled, split);
    mlp1_kernel<<<dim3(HID / 256, BATCH / 8), 256, 0, stream>>>(pooled, W1, b1, hbuf);
    mlp2_norm_kernel<<<BATCH, CDIM, 0, stream>>>(hbuf, W2, b2, out);
    sim_kernel<<<BATCH, BATCH, 0, stream>>>(out, temp, simbuf);
    loss_kernel<<<1, BATCH, 0, stream>>>(simbuf, lang, out + (size_t)BATCH * CDIM);
}

// Round 2
// 242.158 us; speedup vs baseline: 1.4782x; 1.4782x over previous
//
#include <hip/hip_runtime.h>
#include <math.h>

#define BATCH 128
#define SEQ   2048
#define HID   1024
#define CDIM  256
#define SPLIT 16
#define ROWS_PER (SEQ / SPLIT)   // 128

typedef float vf4 __attribute__((ext_vector_type(4)));
typedef int   vi4 __attribute__((ext_vector_type(4)));

// ---------------------------------------------------------------------------
// Kernel 1: partial masked sums over a chunk of the sequence.
// grid (BATCH, SPLIT), block 256. Thread t owns float4 at h = t*4 (256*4=HID).
// Non-temporal loads: features are streamed exactly once (1 GiB > L3).
// ---------------------------------------------------------------------------
__global__ __launch_bounds__(256) void pool_partial_kernel(
    const float* __restrict__ feat, const int* __restrict__ mask,
    float* __restrict__ partial)
{
    const int b     = blockIdx.x;
    const int chunk = blockIdx.y;
    const int t     = threadIdx.x;

    const vf4* fp = reinterpret_cast<const vf4*>(feat) +
                    ((size_t)b * SEQ + (size_t)chunk * ROWS_PER) * (HID / 4);
    const vi4* mp = reinterpret_cast<const vi4*>(
                        mask + (size_t)b * SEQ + (size_t)chunk * ROWS_PER);

    vf4 acc = {0.f, 0.f, 0.f, 0.f};
    for (int s = 0; s < ROWS_PER; s += 8) {
        const vi4 m0 = mp[s / 4];
        const vi4 m1 = mp[s / 4 + 1];
        float mm[8];
        mm[0] = (float)m0.x; mm[1] = (float)m0.y; mm[2] = (float)m0.z; mm[3] = (float)m0.w;
        mm[4] = (float)m1.x; mm[5] = (float)m1.y; mm[6] = (float)m1.z; mm[7] = (float)m1.w;
        #pragma unroll
        for (int u = 0; u < 8; ++u) {
            const vf4 v = __builtin_nontemporal_load(&fp[(size_t)(s + u) * (HID / 4) + t]);
            acc += v * mm[u];
        }
    }
    reinterpret_cast<vf4*>(partial)[((size_t)b * SPLIT + chunk) * (HID / 4) + t] = acc;
}

// ---------------------------------------------------------------------------
// Kernel 2: mask count + reduce partials + divide -> pooled [B,H].
// grid BATCH, block 256 (float4 per thread).
// ---------------------------------------------------------------------------
__global__ __launch_bounds__(256) void pool_final_kernel(
    const float* __restrict__ partial, const int* __restrict__ mask,
    float* __restrict__ pooled)
{
    const int b = blockIdx.x;
    const int t = threadIdx.x;

    int local = 0;
    #pragma unroll
    for (int s = t; s < SEQ; s += 256) local += mask[(size_t)b * SEQ + s];
    __shared__ int redi[256];
    redi[t] = local;
    __syncthreads();
    for (int off = 128; off > 0; off >>= 1) {
        if (t < off) redi[t] += redi[t + off];
        __syncthreads();
    }
    const float inv = 1.0f / (float)redi[0];

    vf4 a = {0.f, 0.f, 0.f, 0.f};
    #pragma unroll
    for (int c = 0; c < SPLIT; ++c)
        a += reinterpret_cast<const vf4*>(partial)[((size_t)b * SPLIT + c) * (HID / 4) + t];
    a *= inv;
    reinterpret_cast<vf4*>(pooled)[(size_t)b * (HID / 4) + t] = a;
}

// ---------------------------------------------------------------------------
// Kernel 3: h = relu(pooled @ W1 + b1).  W1 is [H,H] (in,out) row-major.
// grid (HID/256, BATCH/2) = (4,64) -> 256 blocks (all CUs), 2 rows/block.
// k-loop unrolled x8 -> 8 coalesced W1 loads in flight per thread.
// ---------------------------------------------------------------------------
__global__ __launch_bounds__(256) void mlp1_kernel(
    const float* __restrict__ pooled, const float* __restrict__ W1,
    const float* __restrict__ b1, float* __restrict__ hout)
{
    __shared__ float ps[2 * HID];  // 8 KiB
    const int jc = blockIdx.x;
    const int b0 = blockIdx.y * 2;
    const int t  = threadIdx.x;

    const vf4* src = reinterpret_cast<const vf4*>(pooled + (size_t)b0 * HID);
    vf4* dst = reinterpret_cast<vf4*>(ps);
    #pragma unroll
    for (int i = 0; i < 2; ++i) dst[t + i * 256] = src[t + i * 256];
    __syncthreads();

    const int j = jc * 256 + t;
    float a0 = 0.f, a1 = 0.f;
    for (int k = 0; k < HID; k += 8) {
        float w[8];
        #pragma unroll
        for (int u = 0; u < 8; ++u) w[u] = W1[(size_t)(k + u) * HID + j];
        #pragma unroll
        for (int u = 0; u < 8; ++u) {
            a0 = fmaf(ps[k + u],       w[u], a0);
            a1 = fmaf(ps[HID + k + u], w[u], a1);
        }
    }
    const float bias = b1[j];
    hout[(size_t)b0 * HID + j]       = fmaxf(a0 + bias, 0.f);
    hout[(size_t)(b0 + 1) * HID + j] = fmaxf(a1 + bias, 0.f);
}

// ---------------------------------------------------------------------------
// Kernel 4: proj = normalize(h @ W2 + b2). W2 is [H,C]. grid BATCH, block CDIM.
// Writes normalized proj directly into d_out. k-loop unrolled x8.
// ---------------------------------------------------------------------------
__global__ __launch_bounds__(256) void mlp2_norm_kernel(
    const float* __restrict__ hin, const float* __restrict__ W2,
    const float* __restrict__ b2, float* __restrict__ proj)
{
    __shared__ float hs[HID];  // 4 KiB
    const int b = blockIdx.x;
    const int t = threadIdx.x;

    reinterpret_cast<vf4*>(hs)[t] =
        reinterpret_cast<const vf4*>(hin + (size_t)b * HID)[t];
    __syncthreads();

    float acc = 0.f;
    for (int k = 0; k < HID; k += 8) {
        float w[8];
        #pragma unroll
        for (int u = 0; u < 8; ++u) w[u] = W2[(size_t)(k + u) * CDIM + t];
        #pragma unroll
        for (int u = 0; u < 8; ++u) acc = fmaf(hs[k + u], w[u], acc);
    }
    acc += b2[t];

    __shared__ float red[CDIM];
    red[t] = acc * acc;
    __syncthreads();
    for (int off = CDIM / 2; off > 0; off >>= 1) {
        if (t < off) red[t] += red[t + off];
        __syncthreads();
    }
    const float norm = fmaxf(sqrtf(red[0]), 1e-12f);
    proj[(size_t)b * CDIM + t] = acc / norm;
}

// ---------------------------------------------------------------------------
// Kernel 5: fused sim row + per-row loss. grid BATCH, block BATCH.
// Block i: thread j computes sim[i][j], then deterministic tree reduces for
// max / sum-exp / label-weighted sum. Writes loss_i to ws.
// ---------------------------------------------------------------------------
__global__ __launch_bounds__(128) void sim_loss_kernel(
    const float* __restrict__ proj, const float* __restrict__ temp,
    const int* __restrict__ lang, float* __restrict__ loss_part)
{
    const int i = blockIdx.x;
    const int j = threadIdx.x;

    __shared__ float pi[CDIM];
    if (j < CDIM / 4)
        reinterpret_cast<vf4*>(pi)[j] =
            reinterpret_cast<const vf4*>(proj + (size_t)i * CDIM)[j];
    __syncthreads();

    const vf4* pj = reinterpret_cast<const vf4*>(proj + (size_t)j * CDIM);
    float acc = 0.f;
    #pragma unroll 8
    for (int c = 0; c < CDIM / 4; ++c) {
        const vf4 v = pj[c];
        acc = fmaf(pi[4 * c + 0], v.x, acc);
        acc = fmaf(pi[4 * c + 1], v.y, acc);
        acc = fmaf(pi[4 * c + 2], v.z, acc);
        acc = fmaf(pi[4 * c + 3], v.w, acc);
    }
    const float s = acc / temp[0];
    const int li = lang[i];

    __shared__ float r1[BATCH];
    __shared__ int   ci[BATCH];

    // row max
    r1[j] = s;
    __syncthreads();
    for (int off = BATCH / 2; off > 0; off >>= 1) {
        if (j < off) r1[j] = fmaxf(r1[j], r1[j + off]);
        __syncthreads();
    }
    const float m = r1[0];
    __syncthreads();

    // sum exp
    r1[j] = expf(s - m);
    __syncthreads();
    for (int off = BATCH / 2; off > 0; off >>= 1) {
        if (j < off) r1[j] += r1[j + off];
        __syncthreads();
    }
    const float lse = m + logf(r1[0]);
    __syncthreads();

    // label-weighted sum + count
    const bool sel = (lang[j] != li) && (j != i);
    r1[j] = sel ? s : 0.f;
    ci[j] = sel ? 1 : 0;
    __syncthreads();
    for (int off = BATCH / 2; off > 0; off >>= 1) {
        if (j < off) { r1[j] += r1[j + off]; ci[j] += ci[j + off]; }
        __syncthreads();
    }
    if (j == 0) loss_part[i] = (float)ci[0] * lse - r1[0];
}

// ---------------------------------------------------------------------------
// Kernel 6: mean of per-row losses -> out[B*C].
// ---------------------------------------------------------------------------
__global__ __launch_bounds__(128) void loss_reduce_kernel(
    const float* __restrict__ loss_part, float* __restrict__ out)
{
    const int t = threadIdx.x;
    __shared__ float red[BATCH];
    red[t] = loss_part[t];
    __syncthreads();
    for (int off = BATCH / 2; off > 0; off >>= 1) {
        if (t < off) red[t] += red[t + off];
        __syncthreads();
    }
    if (t == 0) out[0] = red[0] / (float)BATCH;
}

// ---------------------------------------------------------------------------
extern "C" void kernel_launch(void* const* d_in, const int* in_sizes, int n_in,
                              void* d_out, int out_size, void* d_ws, size_t ws_size,
                              hipStream_t stream)
{
    const float* feat = (const float*)d_in[0];
    const float* W1   = (const float*)d_in[1];
    const float* b1   = (const float*)d_in[2];
    const float* W2   = (const float*)d_in[3];
    const float* b2   = (const float*)d_in[4];
    const float* temp = (const float*)d_in[5];
    const int*   lang = (const int*)d_in[6];
    const int*   amask= (const int*)d_in[7];
    float* out = (float*)d_out;
    float* ws  = (float*)d_ws;

    float* partial   = ws;                                       // B*SPLIT*H
    float* pooled    = partial + (size_t)BATCH * SPLIT * HID;    // B*H
    float* hbuf      = pooled + (size_t)BATCH * HID;             // B*H
    float* loss_part = hbuf + (size_t)BATCH * HID;               // B

    pool_partial_kernel<<<dim3(BATCH, SPLIT), 256, 0, stream>>>(feat, amask, partial);
    pool_final_kernel<<<BATCH, 256, 0, stream>>>(partial, amask, pooled);
    mlp1_kernel<<<dim3(HID / 256, BATCH / 2), 256, 0, stream>>>(pooled, W1, b1, hbuf);
    mlp2_norm_kernel<<<BATCH, CDIM, 0, stream>>>(hbuf, W2, b2, out);
    sim_loss_kernel<<<BATCH, BATCH, 0, stream>>>(out, temp, lang, loss_part);
    loss_reduce_kernel<<<1, BATCH, 0, stream>>>(loss_part, out + (size_t)BATCH * CDIM);
}

// Round 3
// 206.426 us; speedup vs baseline: 1.7340x; 1.1731x over previous
//
#include <hip/hip_runtime.h>
#include <math.h>

#define BATCH 128
#define SEQ   2048
#define HID   1024
#define CDIM  256
#define SPLIT 16
#define ROWS_PER (SEQ / SPLIT)   // 128
#define KC1   16                 // mlp1 k-chunks (each 64)
#define KC2   4                  // mlp2 k-chunks (each 256)

typedef float vf4 __attribute__((ext_vector_type(4)));
typedef int   vi4 __attribute__((ext_vector_type(4)));

// ---------------------------------------------------------------------------
// Kernel 1: partial masked sums over a chunk of the sequence.
// grid (BATCH, SPLIT), block 256. Thread t owns float4 at h = t*4 (256*4=HID).
// Non-temporal: features are streamed exactly once (1 GiB > L3).
// ---------------------------------------------------------------------------
__global__ __launch_bounds__(256) void pool_partial_kernel(
    const float* __restrict__ feat, const int* __restrict__ mask,
    float* __restrict__ partial)
{
    const int b     = blockIdx.x;
    const int chunk = blockIdx.y;
    const int t     = threadIdx.x;

    const vf4* fp = reinterpret_cast<const vf4*>(feat) +
                    ((size_t)b * SEQ + (size_t)chunk * ROWS_PER) * (HID / 4);
    const vi4* mp = reinterpret_cast<const vi4*>(
                        mask + (size_t)b * SEQ + (size_t)chunk * ROWS_PER);

    vf4 acc = {0.f, 0.f, 0.f, 0.f};
    for (int s = 0; s < ROWS_PER; s += 8) {
        const vi4 m0 = mp[s / 4];
        const vi4 m1 = mp[s / 4 + 1];
        float mm[8];
        mm[0] = (float)m0.x; mm[1] = (float)m0.y; mm[2] = (float)m0.z; mm[3] = (float)m0.w;
        mm[4] = (float)m1.x; mm[5] = (float)m1.y; mm[6] = (float)m1.z; mm[7] = (float)m1.w;
        #pragma unroll
        for (int u = 0; u < 8; ++u) {
            const vf4 v = __builtin_nontemporal_load(&fp[(size_t)(s + u) * (HID / 4) + t]);
            acc += v * mm[u];
        }
    }
    reinterpret_cast<vf4*>(partial)[((size_t)b * SPLIT + chunk) * (HID / 4) + t] = acc;
}

// ---------------------------------------------------------------------------
// Kernel 2: mask count + reduce partials + divide -> pooled [B,H].
// grid (BATCH, 4), block 256. Block (b,cc) handles cols cc*256..+256.
// ---------------------------------------------------------------------------
__global__ __launch_bounds__(256) void pool_final_kernel(
    const float* __restrict__ partial, const int* __restrict__ mask,
    float* __restrict__ pooled)
{
    const int b  = blockIdx.x;
    const int cc = blockIdx.y;
    const int t  = threadIdx.x;

    int local = 0;
    #pragma unroll
    for (int s = t; s < SEQ; s += 256) local += mask[(size_t)b * SEQ + s];
    __shared__ int redi[256];
    redi[t] = local;
    __syncthreads();
    for (int off = 128; off > 0; off >>= 1) {
        if (t < off) redi[t] += redi[t + off];
        __syncthreads();
    }
    const float inv = 1.0f / (float)redi[0];

    const int col = cc * 256 + t;
    float a = 0.f;
    #pragma unroll
    for (int c = 0; c < SPLIT; ++c)
        a += partial[((size_t)b * SPLIT + c) * HID + col];
    pooled[(size_t)b * HID + col] = a * inv;
}

// ---------------------------------------------------------------------------
// Kernel 3: mlp1 split-K partials. W1 is [H,H] (in,out) row-major.
// grid (4 jc, 16 bg, 16 kc) = 1024 blocks, block 256.
// Block: 8 batch rows x 256 out-cols x 64 k. part1[kc][b][j].
// ---------------------------------------------------------------------------
__global__ __launch_bounds__(256) void mlp1_partial_kernel(
    const float* __restrict__ pooled, const float* __restrict__ W1,
    float* __restrict__ part1)
{
    const int jc = blockIdx.x;
    const int bg = blockIdx.y;
    const int kc = blockIdx.z;
    const int t  = threadIdx.x;

    __shared__ float ps[8][64];  // 2 KiB
    if (t < 128) {
        const int r = t >> 4;
        const int c = (t & 15) * 4;
        *reinterpret_cast<vf4*>(&ps[r][c]) =
            *reinterpret_cast<const vf4*>(&pooled[(size_t)(bg * 8 + r) * HID + kc * 64 + c]);
    }
    __syncthreads();

    const int j = jc * 256 + t;
    const float* w = W1 + (size_t)(kc * 64) * HID + j;

    float acc[8];
    #pragma unroll
    for (int r = 0; r < 8; ++r) acc[r] = 0.f;

    #pragma unroll
    for (int k = 0; k < 64; k += 8) {
        float wv[8];
        #pragma unroll
        for (int u = 0; u < 8; ++u) wv[u] = w[(size_t)(k + u) * HID];
        #pragma unroll
        for (int u = 0; u < 8; ++u) {
            #pragma unroll
            for (int r = 0; r < 8; ++r)
                acc[r] = fmaf(ps[r][k + u], wv[u], acc[r]);
        }
    }
    #pragma unroll
    for (int r = 0; r < 8; ++r)
        part1[((size_t)kc * BATCH + bg * 8 + r) * HID + j] = acc[r];
}

// ---------------------------------------------------------------------------
// Kernel 4: fused {reduce part1 + bias + relu} staging, then mlp2 split-K.
// grid (BATCH, 4 kc) = 512 blocks, block 256 (t = out col j, CDIM=256).
// Each block reduces its own disjoint 256-wide h-chunk (no redundancy).
// part2[kc][b][j].
// ---------------------------------------------------------------------------
__global__ __launch_bounds__(256) void mlp2_partial_kernel(
    const float* __restrict__ part1, const float* __restrict__ b1,
    const float* __restrict__ W2, float* __restrict__ part2)
{
    const int b  = blockIdx.x;
    const int kc = blockIdx.y;
    const int t  = threadIdx.x;

    __shared__ float hs[256];  // 1 KiB
    float s = b1[kc * 256 + t];
    #pragma unroll
    for (int p = 0; p < KC1; ++p)
        s += part1[((size_t)p * BATCH + b) * HID + kc * 256 + t];
    hs[t] = fmaxf(s, 0.f);
    __syncthreads();

    const float* w = W2 + (size_t)(kc * 256) * CDIM + t;
    float acc = 0.f;
    #pragma unroll
    for (int k = 0; k < 256; k += 8) {
        float wv[8];
        #pragma unroll
        for (int u = 0; u < 8; ++u) wv[u] = w[(size_t)(k + u) * CDIM];
        #pragma unroll
        for (int u = 0; u < 8; ++u) acc = fmaf(hs[k + u], wv[u], acc);
    }
    part2[((size_t)kc * BATCH + b) * CDIM + t] = acc;
}

// ---------------------------------------------------------------------------
// Kernel 5: reduce part2 + bias + L2-normalize -> proj (d_out).
// grid BATCH, block CDIM.
// ---------------------------------------------------------------------------
__global__ __launch_bounds__(256) void mlp2_final_kernel(
    const float* __restrict__ part2, const float* __restrict__ b2,
    float* __restrict__ proj)
{
    const int b = blockIdx.x;
    const int t = threadIdx.x;

    float acc = b2[t];
    #pragma unroll
    for (int p = 0; p < KC2; ++p)
        acc += part2[((size_t)p * BATCH + b) * CDIM + t];

    __shared__ float red[CDIM];
    red[t] = acc * acc;
    __syncthreads();
    for (int off = CDIM / 2; off > 0; off >>= 1) {
        if (t < off) red[t] += red[t + off];
        __syncthreads();
    }
    const float norm = fmaxf(sqrtf(red[0]), 1e-12f);
    proj[(size_t)b * CDIM + t] = acc / norm;
}

// ---------------------------------------------------------------------------
// Kernel 6: fused sim row + per-row loss. grid BATCH, block BATCH.
// ---------------------------------------------------------------------------
__global__ __launch_bounds__(128) void sim_loss_kernel(
    const float* __restrict__ proj, const float* __restrict__ temp,
    const int* __restrict__ lang, float* __restrict__ loss_part)
{
    const int i = blockIdx.x;
    const int j = threadIdx.x;

    __shared__ float pi[CDIM];
    if (j < CDIM / 4)
        reinterpret_cast<vf4*>(pi)[j] =
            reinterpret_cast<const vf4*>(proj + (size_t)i * CDIM)[j];
    __syncthreads();

    const vf4* pj = reinterpret_cast<const vf4*>(proj + (size_t)j * CDIM);
    float acc = 0.f;
    #pragma unroll 8
    for (int c = 0; c < CDIM / 4; ++c) {
        const vf4 v = pj[c];
        acc = fmaf(pi[4 * c + 0], v.x, acc);
        acc = fmaf(pi[4 * c + 1], v.y, acc);
        acc = fmaf(pi[4 * c + 2], v.z, acc);
        acc = fmaf(pi[4 * c + 3], v.w, acc);
    }
    const float s = acc / temp[0];
    const int li = lang[i];

    __shared__ float r1[BATCH];
    __shared__ int   ci[BATCH];

    r1[j] = s;
    __syncthreads();
    for (int off = BATCH / 2; off > 0; off >>= 1) {
        if (j < off) r1[j] = fmaxf(r1[j], r1[j + off]);
        __syncthreads();
    }
    const float m = r1[0];
    __syncthreads();

    r1[j] = expf(s - m);
    __syncthreads();
    for (int off = BATCH / 2; off > 0; off >>= 1) {
        if (j < off) r1[j] += r1[j + off];
        __syncthreads();
    }
    const float lse = m + logf(r1[0]);
    __syncthreads();

    const bool sel = (lang[j] != li) && (j != i);
    r1[j] = sel ? s : 0.f;
    ci[j] = sel ? 1 : 0;
    __syncthreads();
    for (int off = BATCH / 2; off > 0; off >>= 1) {
        if (j < off) { r1[j] += r1[j + off]; ci[j] += ci[j + off]; }
        __syncthreads();
    }
    if (j == 0) loss_part[i] = (float)ci[0] * lse - r1[0];
}

// ---------------------------------------------------------------------------
// Kernel 7: mean of per-row losses -> out[B*C].
// ---------------------------------------------------------------------------
__global__ __launch_bounds__(128) void loss_reduce_kernel(
    const float* __restrict__ loss_part, float* __restrict__ out)
{
    const int t = threadIdx.x;
    __shared__ float red[BATCH];
    red[t] = loss_part[t];
    __syncthreads();
    for (int off = BATCH / 2; off > 0; off >>= 1) {
        if (t < off) red[t] += red[t + off];
        __syncthreads();
    }
    if (t == 0) out[0] = red[0] / (float)BATCH;
}

// ---------------------------------------------------------------------------
extern "C" void kernel_launch(void* const* d_in, const int* in_sizes, int n_in,
                              void* d_out, int out_size, void* d_ws, size_t ws_size,
                              hipStream_t stream)
{
    const float* feat = (const float*)d_in[0];
    const float* W1   = (const float*)d_in[1];
    const float* b1   = (const float*)d_in[2];
    const float* W2   = (const float*)d_in[3];
    const float* b2   = (const float*)d_in[4];
    const float* temp = (const float*)d_in[5];
    const int*   lang = (const int*)d_in[6];
    const int*   amask= (const int*)d_in[7];
    float* out = (float*)d_out;
    float* ws  = (float*)d_ws;

    float* partial   = ws;                                        // B*SPLIT*H   (8 MB)
    float* pooled    = partial + (size_t)BATCH * SPLIT * HID;     // B*H
    float* part1     = pooled + (size_t)BATCH * HID;              // KC1*B*H     (8 MB)
    float* part2     = part1 + (size_t)KC1 * BATCH * HID;         // KC2*B*C
    float* loss_part = part2 + (size_t)KC2 * BATCH * CDIM;        // B

    pool_partial_kernel<<<dim3(BATCH, SPLIT), 256, 0, stream>>>(feat, amask, partial);
    pool_final_kernel<<<dim3(BATCH, 4), 256, 0, stream>>>(partial, amask, pooled);
    mlp1_partial_kernel<<<dim3(HID / 256, BATCH / 8, KC1), 256, 0, stream>>>(pooled, W1, part1);
    mlp2_partial_kernel<<<dim3(BATCH, KC2), 256, 0, stream>>>(part1, b1, W2, part2);
    mlp2_final_kernel<<<BATCH, CDIM, 0, stream>>>(part2, b2, out);
    sim_loss_kernel<<<BATCH, BATCH, 0, stream>>>(out, temp, lang, loss_part);
    loss_reduce_kernel<<<1, BATCH, 0, stream>>>(loss_part, out + (size_t)BATCH * CDIM);
}